// Round 21
// baseline (100.069 us; speedup 1.0000x reference)
//
#include <hip/hip_runtime.h>
#include <hip/hip_bf16.h>
#include <cstdint>
#include <cstddef>

typedef unsigned short u16;
typedef short s8v __attribute__((ext_vector_type(8)));
typedef float f4v __attribute__((ext_vector_type(4)));
typedef float f16v __attribute__((ext_vector_type(16)));

#define SEQ   2048
#define BSZ   2
#define HID   1024
#define NH    16
#define DH    64
#define MROWS (BSZ*SEQ)
#define CLOG  0.18033688011112042f   // log2(e)/sqrt(64), folded into Q
#define THR2  6.0f                   // defer-max threshold (log2 units): P <= 64

// f32 -> bf16 round-to-nearest-even
__device__ __forceinline__ u16 f2b(float x) {
  union { float f; uint32_t u; } c; c.f = x;
  uint32_t r = (c.u + 0x7fffu + ((c.u >> 16) & 1u)) >> 16;
  return (u16)r;
}
__device__ __forceinline__ float b2f(u16 v) {
  union { uint32_t u; float f; } c; c.u = (uint32_t)v << 16;
  return c.f;
}

__device__ __forceinline__ f4v mfma16(s8v a, s8v b, f4v c) {
  return __builtin_amdgcn_mfma_f32_16x16x32_bf16(a, b, c, 0, 0, 0);
}
__device__ __forceinline__ f16v mfma32(s8v a, s8v b, f16v c) {
  return __builtin_amdgcn_mfma_f32_32x32x16_bf16(a, b, c, 0, 0, 0);
}

__device__ __forceinline__ float fexp2(float x) {
#if __has_builtin(__builtin_amdgcn_exp2f)
  return __builtin_amdgcn_exp2f(x);
#else
  return exp2f(x);
#endif
}

// pack 2 f32 -> bf16x2 (lo = a, hi = b)
__device__ __forceinline__ uint32_t pkbf16(float a, float b) {
  uint32_t d;
  asm("v_cvt_pk_bf16_f32 %0, %1, %2" : "=v"(d) : "v"(a), "v"(b));
  return d;
}
// v_permlane32_swap_b32 dst,src: new dst = {dst.lo31, src.lo31},
//                                new src = {dst.hi31, src.hi31}
__device__ __forceinline__ void pswap(uint32_t& x, uint32_t& y) {
  asm("v_permlane32_swap_b32 %0, %1" : "+v"(x), "+v"(y));
}

typedef __attribute__((address_space(1))) const void gas_void;
typedef __attribute__((address_space(3))) void las_void;
__device__ __forceinline__ void gload_lds16(const void* g, void* l) {
  __builtin_amdgcn_global_load_lds((gas_void*)g, (las_void*)l, 16, 0, 0);
}

// ---------------- f32 -> bf16 conversion (5 arrays fused) ----------------
__global__ __launch_bounds__(256) void cvt5(
    const float* __restrict__ s0, const float* __restrict__ s1,
    const float* __restrict__ s2, const float* __restrict__ s3,
    const float* __restrict__ s4,
    u16* __restrict__ d0, u16* __restrict__ d1, u16* __restrict__ d2,
    u16* __restrict__ d3, u16* __restrict__ d4)
{
  const float* s; u16* d; int n;
  switch (blockIdx.y) {
    case 0:  s = s0; d = d0; n = MROWS*HID; break;
    case 1:  s = s1; d = d1; n = HID*HID;   break;
    case 2:  s = s2; d = d2; n = HID*HID;   break;
    case 3:  s = s3; d = d3; n = HID*HID;   break;
    default: s = s4; d = d4; n = HID*HID;   break;
  }
  const int n8 = n >> 3;
  const int stride = gridDim.x * blockDim.x;
  for (int i = blockIdx.x * blockDim.x + threadIdx.x; i < n8; i += stride) {
    const float4* p = (const float4*)s + (size_t)i * 2;
    float4 a = p[0], b = p[1];
    s8v ov;
    ov[0] = (short)f2b(a.x); ov[1] = (short)f2b(a.y);
    ov[2] = (short)f2b(a.z); ov[3] = (short)f2b(a.w);
    ov[4] = (short)f2b(b.x); ov[5] = (short)f2b(b.y);
    ov[6] = (short)f2b(b.z); ov[7] = (short)f2b(b.w);
    ((s8v*)d)[i] = ov;
  }
}

// ---------------- QKV GEMM: C = (A[M,K] * B[N,K]^T + bias) * sc ----------------
// 128x128 tile, BK=64 (16 K-steps, 32 MFMA/wave per drain), 4 waves 2x2 (each 64x64).
// G21 swizzled LDS: rows of 128B, chunk g XOR'd with row&7 (involution, bits 4-6).
//   write: linear dest t*16B  <-  global source row t>>3, chunk (t&7)^((t>>3)&7)
//   read:  lane l, row R, k-chunk g  ->  As[R*64 + ((g ^ (R&7))*8)]  (2-way banks, free)
// r13 geometry (correctness-verified) minus its diagnosed killer (bank conflicts).
__global__ __launch_bounds__(256) void gemm_qkv(
    const u16* __restrict__ A,
    const u16* __restrict__ B0, const u16* __restrict__ B1, const u16* __restrict__ B2,
    const float* __restrict__ bias0, const float* __restrict__ bias1, const float* __restrict__ bias2,
    const float sc0, const float sc1, const float sc2,
    void* C0, void* C1, void* C2,
    const int Ksz)
{
  const int bm = blockIdx.x;
  const int bn = blockIdx.y;
  const int z  = blockIdx.z;

  const u16* Bp; const float* bias; void* Cp; float sc;
  if (z == 0)      { Bp = B0; bias = bias0; Cp = C0; sc = sc0; }
  else if (z == 1) { Bp = B1; bias = bias1; Cp = C1; sc = sc1; }
  else             { Bp = B2; bias = bias2; Cp = C2; sc = sc2; }

  __shared__ __align__(16) u16 As[128 * 64];   // 16 KB, swizzled
  __shared__ __align__(16) u16 Bs[128 * 64];   // 16 KB, swizzled

  const int t  = threadIdx.x;
  const int w  = t >> 6;
  const int l  = t & 63;
  const int lr = l & 15;
  const int lg = l >> 4;
  const int wr = w >> 1;
  const int wc = w & 1;

  const int trow = t >> 3;                       // 0..31
  const int gsc  = ((t & 7) ^ (trow & 7)) * 8;   // u16 offset in row

  const u16* gA = A  + (size_t)(bm * 128 + trow) * Ksz + gsc;
  const u16* gB = Bp + (size_t)(bn * 128 + trow) * Ksz + gsc;
  const size_t rk32 = (size_t)32 * Ksz;

  const f4v fzero = {0.f, 0.f, 0.f, 0.f};
  f4v acc[4][4];
#pragma unroll
  for (int m = 0; m < 4; ++m)
#pragma unroll
    for (int n = 0; n < 4; ++n) acc[m][n] = fzero;

  const int nk = Ksz >> 6;   // BK=64
  for (int kt = 0; kt < nk; ++kt) {
    if (kt) __syncthreads();
    gload_lds16(gA,            &As[t * 8]);            // rows  0..31
    gload_lds16(gA + rk32,     &As[2048 + t * 8]);     // rows 32..63
    gload_lds16(gA + 2 * rk32, &As[4096 + t * 8]);     // rows 64..95
    gload_lds16(gA + 3 * rk32, &As[6144 + t * 8]);     // rows 96..127
    gload_lds16(gB,            &Bs[t * 8]);
    gload_lds16(gB + rk32,     &Bs[2048 + t * 8]);
    gload_lds16(gB + 2 * rk32, &Bs[4096 + t * 8]);
    gload_lds16(gB + 3 * rk32, &Bs[6144 + t * 8]);
    gA += 64; gB += 64;
    __syncthreads();

#pragma unroll
    for (int kk = 0; kk < 2; ++kk) {
      s8v af[4], bfr[4];
#pragma unroll
      for (int m = 0; m < 4; ++m) {
        const int R = wr * 64 + m * 16 + lr;
        const int g = (kk * 4 + lg) ^ (lr & 7);
        af[m] = *(const s8v*)&As[R * 64 + g * 8];
      }
#pragma unroll
      for (int n = 0; n < 4; ++n) {
        const int R = wc * 64 + n * 16 + lr;
        const int g = (kk * 4 + lg) ^ (lr & 7);
        bfr[n] = *(const s8v*)&Bs[R * 64 + g * 8];
      }
#pragma unroll
      for (int m = 0; m < 4; ++m)
#pragma unroll
        for (int n = 0; n < 4; ++n)
          acc[m][n] = mfma16(af[m], bfr[n], acc[m][n]);
    }
  }

  // epilogue: C/D layout col = lane&15, row = (lane>>4)*4 + reg  (r11/r13-verified)
  if (z == 1) {
    // K' fragment-paged scatter
#pragma unroll
    for (int n = 0; n < 4; ++n) {
      const int col = bn * 128 + wc * 64 + n * 16 + lr;
      const float bv = bias[col];
      const int h  = col >> 6;
      const int d6 = col & 63;
      const int j  = d6 >> 4;
      const int hic = (d6 >> 3) & 1;
      const int e  = d6 & 7;
#pragma unroll
      for (int m = 0; m < 4; ++m) {
#pragma unroll
        for (int r = 0; r < 4; ++r) {
          const int row = bm * 128 + wr * 64 + m * 16 + lg * 4 + r;
          const int bb = row >> 11;
          const int s  = row & (SEQ - 1);
          const int tile = s >> 5;
          const int l31r = s & 31;
          const size_t idx = ((((size_t)(bb * NH + h) * 64 + tile) * 4 + j) * 512)
                           + (size_t)hic * 256 + (size_t)l31r * 8 + e;
          ((u16*)Cp)[idx] = f2b((acc[m][n][r] + bv) * sc);
        }
      }
    }
  } else if (z == 2) {
    // V' fragment-paged quad store
#pragma unroll
    for (int n = 0; n < 4; ++n) {
      const int col = bn * 128 + wc * 64 + n * 16 + lr;
      const float bv = bias[col];
      const int h    = col >> 6;
      const int dt   = (col >> 5) & 1;
      const int l31c = col & 31;
#pragma unroll
      for (int m = 0; m < 4; ++m) {
        const int row0 = bm * 128 + wr * 64 + m * 16 + lg * 4;
        const int bb = row0 >> 11;
        const int s0 = row0 & (SEQ - 1);
        const int tile = s0 >> 5;
        const int u    = (s0 >> 4) & 1;
        const int hiw  = (s0 >> 3) & 1;
        const int e0   = s0 & 7;
        const size_t idx = ((((size_t)(bb * NH + h) * 64 + tile) * 2 + u) * 2 + dt) * 512
                         + (size_t)hiw * 256 + (size_t)l31c * 8 + e0;
        ushort4 pk;
        pk.x = f2b((acc[m][n][0] + bv) * sc);
        pk.y = f2b((acc[m][n][1] + bv) * sc);
        pk.z = f2b((acc[m][n][2] + bv) * sc);
        pk.w = f2b((acc[m][n][3] + bv) * sc);
        *(ushort4*)((u16*)Cp + idx) = pk;
      }
    }
  } else {
    // Q row-major bf16 (pre-scaled)
#pragma unroll
    for (int n = 0; n < 4; ++n) {
      const int col = bn * 128 + wc * 64 + n * 16 + lr;
      const float bv = bias[col];
#pragma unroll
      for (int m = 0; m < 4; ++m) {
#pragma unroll
        for (int r = 0; r < 4; ++r) {
          const int row = bm * 128 + wr * 64 + m * 16 + lg * 4 + r;
          ((u16*)Cp)[(size_t)row * HID + col] = f2b((acc[m][n][r] + bv) * sc);
        }
      }
    }
  }
}

// ---------------- output projection: C[M,N] f32 = A[M,K] * B[N,K]^T + bias ----------------
// 64x64 tile, BK=128 (8 K-steps, 16 MFMA/wave per drain), 4 waves 2x2 (each 32x32).
// G21 swizzled LDS: rows of 256B = 16 chunks; store global chunk c^(row&15) at chunk c.
__global__ __launch_bounds__(256) void gemm_out(
    const u16* __restrict__ A, const u16* __restrict__ B,
    const float* __restrict__ bias, float* __restrict__ C, const int Ksz, const int Nsz)
{
  const int bm = blockIdx.x;
  const int bn = blockIdx.y;

  __shared__ __align__(16) u16 As[64 * 128];   // 16 KB
  __shared__ __align__(16) u16 Bs[64 * 128];   // 16 KB

  const int t  = threadIdx.x;
  const int w  = t >> 6;
  const int l  = t & 63;
  const int lr = l & 15;
  const int lg = l >> 4;
  const int wr = w >> 1;
  const int wc = w & 1;

  const int trow = t >> 4;                        // 0..15
  const int gsc  = ((t & 15) ^ trow) * 8;         // u16 offset in row (chunk swizzle)

  const u16* gA = A + (size_t)(bm * 64 + trow) * Ksz + gsc;
  const u16* gB = B + (size_t)(bn * 64 + trow) * Ksz + gsc;
  const size_t rk16 = (size_t)16 * Ksz;

  const f4v fzero = {0.f, 0.f, 0.f, 0.f};
  f4v acc[2][2];
#pragma unroll
  for (int m = 0; m < 2; ++m)
#pragma unroll
    for (int n = 0; n < 2; ++n) acc[m][n] = fzero;

  const int nk = Ksz >> 7;   // BK=128
  for (int kt = 0; kt < nk; ++kt) {
    if (kt) __syncthreads();
    gload_lds16(gA,            &As[t * 8]);           // rows  0..15
    gload_lds16(gA + rk16,     &As[2048 + t * 8]);    // rows 16..31
    gload_lds16(gA + 2 * rk16, &As[4096 + t * 8]);    // rows 32..47
    gload_lds16(gA + 3 * rk16, &As[6144 + t * 8]);    // rows 48..63
    gload_lds16(gB,            &Bs[t * 8]);
    gload_lds16(gB + rk16,     &Bs[2048 + t * 8]);
    gload_lds16(gB + 2 * rk16, &Bs[4096 + t * 8]);
    gload_lds16(gB + 3 * rk16, &Bs[6144 + t * 8]);
    gA += 128; gB += 128;
    __syncthreads();

#pragma unroll
    for (int kk = 0; kk < 4; ++kk) {
      s8v af[2], bfr[2];
#pragma unroll
      for (int m = 0; m < 2; ++m) {
        const int R = wr * 32 + m * 16 + lr;
        const int g = (kk * 4 + lg) ^ lr;
        af[m] = *(const s8v*)&As[R * 128 + g * 8];
      }
#pragma unroll
      for (int n = 0; n < 2; ++n) {
        const int R = wc * 32 + n * 16 + lr;
        const int g = (kk * 4 + lg) ^ lr;
        bfr[n] = *(const s8v*)&Bs[R * 128 + g * 8];
      }
#pragma unroll
      for (int m = 0; m < 2; ++m)
#pragma unroll
        for (int n = 0; n < 2; ++n)
          acc[m][n] = mfma16(af[m], bfr[n], acc[m][n]);
    }
  }

#pragma unroll
  for (int n = 0; n < 2; ++n) {
    const int col = bn * 64 + wc * 32 + n * 16 + lr;
    const float bv = bias[col];
#pragma unroll
    for (int m = 0; m < 2; ++m) {
#pragma unroll
      for (int r = 0; r < 4; ++r) {
        const int row = bm * 64 + wr * 32 + m * 16 + lg * 4 + r;
        C[(size_t)row * Nsz + col] = acc[m][n][r] + bv;
      }
    }
  }
}

// ---------------- fused causal attention (swapped QK^T, 32x32 MFMA) ----------------
// grid (16, 2, 64), 256 threads = 4 waves: block = (head, batch, one qt = 63-z, LPT).
// 2048 blocks = 8 blocks/CU = 32 waves/CU; LPT order backfills the triangular tail.
// K/V from fragment-paged K'/V' (lane-contiguous 1KB loads). 4 waves split KV tiles
// by kt % 4; lane-local softmax; 4-way flash merge (bf16 Oacc).
// S^T = mfma(A=K, B=Q): lane l holds S[q = l&31, kv = (r&3)+8*(r>>2)+4*(l>>5)].
// O regs: o[r] = O[q = (r&3)+8*(r>>2)+4*hi, d = l&31 (+32 for o1)]  (C/D layout).
__global__ __launch_bounds__(256, 4) void attn_fused(
    const u16* __restrict__ Qm, const u16* __restrict__ Kp,
    const u16* __restrict__ Vp, u16* __restrict__ Om)
{
  __shared__ __align__(16) u16 Oaccb[4 * 32 * 66];   // bf16 partials (18 KB total LDS)
  __shared__ float Msh[4][32];
  __shared__ float Lsh[4][32];
  __shared__ float Rsh[4][32];

  const int h  = blockIdx.x;
  const int b  = blockIdx.y;
  const int qt = 63 - blockIdx.z;   // longest-first dispatch (LPT)
  const int t  = threadIdx.x;
  const int w  = t >> 6;        // 0..3
  const int l  = t & 63;
  const int l31 = l & 31;
  const int hi  = l >> 5;
  const int hi8 = hi * 8;
  const int hi4 = hi * 4;

  const u16* Qb = Qm + (size_t)(b * SEQ) * HID + h * DH;
  const u16* Kpb = Kp + (size_t)(b * NH + h) * 64 * 2048 + (size_t)l * 8;
  const u16* Vpb = Vp + (size_t)(b * NH + h) * 64 * 2048 + (size_t)l * 8;

  const f16v z16 = {0.f,0.f,0.f,0.f,0.f,0.f,0.f,0.f,0.f,0.f,0.f,0.f,0.f,0.f,0.f,0.f};

  const int qr0 = qt * 32;

  // Q fragments (B-operand): lane -> col q = l31, k = d
  const u16* qrow = Qb + (size_t)(qr0 + l31) * HID + hi8;
  const s8v q0 = *(const s8v*)(qrow);
  const s8v q1 = *(const s8v*)(qrow + 16);
  const s8v q2 = *(const s8v*)(qrow + 32);
  const s8v q3 = *(const s8v*)(qrow + 48);

  f16v o0 = z16, o1 = z16;
  float mrow = -1e30f, lrow = 0.f;

  for (int kt = w; kt <= qt; kt += 4) {
    // K fragments: lane-contiguous pages (j = 0..3)
    const u16* ktb = Kpb + (size_t)kt * 2048;
    const s8v ak0 = *(const s8v*)(ktb);
    const s8v ak1 = *(const s8v*)(ktb + 512);
    const s8v ak2 = *(const s8v*)(ktb + 1024);
    const s8v ak3 = *(const s8v*)(ktb + 1536);
    // V^T fragments: lane-contiguous pages (u, dt)
    const u16* vtb = Vpb + (size_t)kt * 2048;
    const s8v bv00 = *(const s8v*)(vtb);          // u=0 dt=0
    const s8v bv01 = *(const s8v*)(vtb + 512);    // u=0 dt=1
    const s8v bv10 = *(const s8v*)(vtb + 1024);   // u=1 dt=0
    const s8v bv11 = *(const s8v*)(vtb + 1536);   // u=1 dt=1

    // S^T tile
    f16v st = z16;
    __builtin_amdgcn_s_setprio(1);
    st = mfma32(ak0, q0, st);
    st = mfma32(ak1, q1, st);
    st = mfma32(ak2, q2, st);
    st = mfma32(ak3, q3, st);
    __builtin_amdgcn_s_setprio(0);

    if (kt == qt) {   // causal mask, diagonal tile only (kv0 == qr0)
#pragma unroll
      for (int r = 0; r < 16; ++r)
        if (((r & 3) + 8 * (r >> 2) + hi4) > l31) st[r] = -1e30f;
    }

    // row max: in-register tree + cross-half swap
    float a0 = fmaxf(st[0], st[8]),  a1 = fmaxf(st[1], st[9]);
    float a2 = fmaxf(st[2], st[10]), a3 = fmaxf(st[3], st[11]);
    float a4 = fmaxf(st[4], st[12]), a5 = fmaxf(st[5], st[13]);
    float a6 = fmaxf(st[6], st[14]), a7 = fmaxf(st[7], st[15]);
    float b0 = fmaxf(a0, a4), b1 = fmaxf(a1, a5), b2 = fmaxf(a2, a6), b3 = fmaxf(a3, a7);
    float tm = fmaxf(fmaxf(b0, b1), fmaxf(b2, b3));
    tm = fmaxf(tm, __shfl_xor(tm, 32, 64));

    // defer-max: rescale only when some row's max grew past THR2
    if (!__all((tm - mrow <= THR2) ? 1 : 0)) {
      const float mn = fmaxf(mrow, tm);
      const float rs = fexp2(mrow - mn);
      mrow = mn;
      lrow *= rs;
      if (l < 32) Rsh[w][l31] = rs;
#pragma unroll
      for (int r = 0; r < 16; ++r) {
        const float f = Rsh[w][(r & 3) + 8 * (r >> 2) + hi4];
        o0[r] *= f; o1[r] *= f;
      }
    }

    // P = 2^(s - m), lane-local
    float p[16];
#pragma unroll
    for (int r = 0; r < 16; ++r) p[r] = fexp2(st[r] - mrow);

    // row sum: tree + cross-half swap
    float u0 = p[0]+p[8],  u1 = p[1]+p[9],  u2 = p[2]+p[10], u3 = p[3]+p[11];
    float u4 = p[4]+p[12], u5 = p[5]+p[13], u6 = p[6]+p[14], u7 = p[7]+p[15];
    float v0 = u0+u4, v1 = u1+u5, v2 = u2+u6, v3 = u3+u7;
    float ts = (v0+v1) + (v2+v3);
    ts += __shfl_xor(ts, 32, 64);
    lrow += ts;

    // P -> bf16 A-fragments via cvt_pk + permlane32_swap (m214 recipe).
    // pswap(X, Y): X <- {X.lo31, Y.lo31} (= word j), Y <- {X.hi31, Y.hi31} (= word j+2)
    uint32_t A0 = pkbf16(p[0], p[1]),  A1 = pkbf16(p[2], p[3]);
    uint32_t B0 = pkbf16(p[4], p[5]),  B1 = pkbf16(p[6], p[7]);
    pswap(A0, B0); pswap(A1, B1);
    uint32_t C0 = pkbf16(p[8], p[9]),  C1 = pkbf16(p[10], p[11]);
    uint32_t D0 = pkbf16(p[12], p[13]), D1 = pkbf16(p[14], p[15]);
    pswap(C0, D0); pswap(C1, D1);
    union { uint32_t wd[4]; s8v v; } f0, f1;
    f0.wd[0] = A0; f0.wd[1] = A1; f0.wd[2] = B0; f0.wd[3] = B1;   // kv 0..15
    f1.wd[0] = C0; f1.wd[1] = C1; f1.wd[2] = D0; f1.wd[3] = D1;   // kv 16..31

    // O += P V
    __builtin_amdgcn_s_setprio(1);
    o0 = mfma32(f0.v, bv00, o0);
    o0 = mfma32(f1.v, bv10, o0);
    o1 = mfma32(f0.v, bv01, o1);
    o1 = mfma32(f1.v, bv11, o1);
    __builtin_amdgcn_s_setprio(0);
  }

  // ---- flash merge of the 4 waves' partials (bf16 Oacc) ----
  if (l < 32) { Msh[w][l31] = mrow; Lsh[w][l31] = lrow; }
  __syncthreads();

  float fr[16];
#pragma unroll
  for (int r = 0; r < 16; ++r) {
    const int q = (r & 3) + 8 * (r >> 2) + hi4;
    float M = fmaxf(fmaxf(Msh[0][q], Msh[1][q]), fmaxf(Msh[2][q], Msh[3][q]));
    // own-wave max for row q from Msh (register mrow is row l31's max)
    fr[r] = fexp2(Msh[w][q] - M);
  }
#pragma unroll
  for (int r = 0; r < 16; ++r) {
    const int q = (r & 3) + 8 * (r >> 2) + hi4;
    Oaccb[(w * 32 + q) * 66 + l31]      = f2b(o0[r] * fr[r]);
    Oaccb[(w * 32 + q) * 66 + 33 + l31] = f2b(o1[r] * fr[r]);
  }
  __syncthreads();

  // sum phase: wave w -> rows w*8..w*8+7, lane l -> column d
#pragma unroll
  for (int j = 0; j < 8; ++j) {
    const int row = w * 8 + j;
    float M = fmaxf(fmaxf(Msh[0][row], Msh[1][row]), fmaxf(Msh[2][row], Msh[3][row]));
    float lt = 0.f;
#pragma unroll
    for (int wp = 0; wp < 4; ++wp) lt += fexp2(Msh[wp][row] - M) * Lsh[wp][row];
    const int cof = (l >= 32) ? (33 + l31) : l31;
    float v = 0.f;
#pragma unroll
    for (int wp = 0; wp < 4; ++wp) v += b2f(Oaccb[(wp * 32 + row) * 66 + cof]);
    Om[(size_t)(b * SEQ + qr0 + row) * HID + h * DH + l] = f2b(v / lt);
  }
}

// ---------------- launch ----------------
extern "C" void kernel_launch(void* const* d_in, const int* in_sizes, int n_in,
                              void* d_out, int out_size, void* d_ws, size_t ws_size,
                              hipStream_t stream) {
  const float* x  = (const float*)d_in[0];
  const float* Wq = (const float*)d_in[1];
  const float* bq = (const float*)d_in[2];
  const float* Wk = (const float*)d_in[3];
  const float* bk = (const float*)d_in[4];
  const float* Wv = (const float*)d_in[5];
  const float* bv = (const float*)d_in[6];
  const float* Wm = (const float*)d_in[7];
  const float* bm = (const float*)d_in[8];
  float* out = (float*)d_out;

  u16* xb  = (u16*)d_ws;
  u16* Wqb = xb  + (size_t)MROWS * HID;
  u16* Wkb = Wqb + (size_t)HID * HID;
  u16* Wvb = Wkb + (size_t)HID * HID;
  u16* Wmb = Wvb + (size_t)HID * HID;
  u16* Qm  = Wmb + (size_t)HID * HID;
  u16* Kp  = Qm  + (size_t)MROWS * HID;   // K fragment-paged
  u16* Vp  = Kp  + (size_t)MROWS * HID;   // V fragment-paged
  u16* att = Vp  + (size_t)MROWS * HID;

  cvt5<<<dim3(512, 5, 1), 256, 0, stream>>>(x, Wq, Wk, Wv, Wm, xb, Wqb, Wkb, Wvb, Wmb);
  gemm_qkv<<<dim3(32, 8, 3), 256, 0, stream>>>(
      xb, Wqb, Wkb, Wvb, bq, bk, bv, CLOG, 1.f, 1.f, Qm, Kp, Vp, HID);
  attn_fused<<<dim3(16, 2, 64), 256, 0, stream>>>(Qm, Kp, Vp, att);
  gemm_out<<<dim3(64, 16), 256, 0, stream>>>(att, Wmb, bm, out, HID, HID);
}

// Round 22
// 94.569 us; speedup vs baseline: 1.0582x; 1.0582x over previous
//
#include <hip/hip_runtime.h>
#include <hip/hip_bf16.h>
#include <cstdint>
#include <cstddef>

typedef unsigned short u16;
typedef short s8v __attribute__((ext_vector_type(8)));
typedef float f4v __attribute__((ext_vector_type(4)));
typedef float f16v __attribute__((ext_vector_type(16)));

#define SEQ   2048
#define BSZ   2
#define HID   1024
#define NH    16
#define DH    64
#define MROWS (BSZ*SEQ)
#define CLOG  0.18033688011112042f   // log2(e)/sqrt(64), folded into Q
#define THR2  6.0f                   // defer-max threshold (log2 units): P <= 64

// f32 -> bf16 round-to-nearest-even
__device__ __forceinline__ u16 f2b(float x) {
  union { float f; uint32_t u; } c; c.f = x;
  uint32_t r = (c.u + 0x7fffu + ((c.u >> 16) & 1u)) >> 16;
  return (u16)r;
}
__device__ __forceinline__ float b2f(u16 v) {
  union { uint32_t u; float f; } c; c.u = (uint32_t)v << 16;
  return c.f;
}

__device__ __forceinline__ f4v mfma16(s8v a, s8v b, f4v c) {
  return __builtin_amdgcn_mfma_f32_16x16x32_bf16(a, b, c, 0, 0, 0);
}
__device__ __forceinline__ f16v mfma32(s8v a, s8v b, f16v c) {
  return __builtin_amdgcn_mfma_f32_32x32x16_bf16(a, b, c, 0, 0, 0);
}

__device__ __forceinline__ float fexp2(float x) {
#if __has_builtin(__builtin_amdgcn_exp2f)
  return __builtin_amdgcn_exp2f(x);
#else
  return exp2f(x);
#endif
}

// pack 2 f32 -> bf16x2 (lo = a, hi = b)
__device__ __forceinline__ uint32_t pkbf16(float a, float b) {
  uint32_t d;
  asm("v_cvt_pk_bf16_f32 %0, %1, %2" : "=v"(d) : "v"(a), "v"(b));
  return d;
}
// v_permlane32_swap_b32 dst,src: new dst = {dst.lo31, src.lo31},
//                                new src = {dst.hi31, src.hi31}
__device__ __forceinline__ void pswap(uint32_t& x, uint32_t& y) {
  asm("v_permlane32_swap_b32 %0, %1" : "+v"(x), "+v"(y));
}

typedef __attribute__((address_space(1))) const void gas_void;
typedef __attribute__((address_space(3))) void las_void;
__device__ __forceinline__ void gload_lds16(const void* g, void* l) {
  __builtin_amdgcn_global_load_lds((gas_void*)g, (las_void*)l, 16, 0, 0);
}

// ---------------- f32 -> bf16 conversion (5 arrays fused) ----------------
__global__ __launch_bounds__(256) void cvt5(
    const float* __restrict__ s0, const float* __restrict__ s1,
    const float* __restrict__ s2, const float* __restrict__ s3,
    const float* __restrict__ s4,
    u16* __restrict__ d0, u16* __restrict__ d1, u16* __restrict__ d2,
    u16* __restrict__ d3, u16* __restrict__ d4)
{
  const float* s; u16* d; int n;
  switch (blockIdx.y) {
    case 0:  s = s0; d = d0; n = MROWS*HID; break;
    case 1:  s = s1; d = d1; n = HID*HID;   break;
    case 2:  s = s2; d = d2; n = HID*HID;   break;
    case 3:  s = s3; d = d3; n = HID*HID;   break;
    default: s = s4; d = d4; n = HID*HID;   break;
  }
  const int n8 = n >> 3;
  const int stride = gridDim.x * blockDim.x;
  for (int i = blockIdx.x * blockDim.x + threadIdx.x; i < n8; i += stride) {
    const float4* p = (const float4*)s + (size_t)i * 2;
    float4 a = p[0], b = p[1];
    s8v ov;
    ov[0] = (short)f2b(a.x); ov[1] = (short)f2b(a.y);
    ov[2] = (short)f2b(a.z); ov[3] = (short)f2b(a.w);
    ov[4] = (short)f2b(b.x); ov[5] = (short)f2b(b.y);
    ov[6] = (short)f2b(b.z); ov[7] = (short)f2b(b.w);
    ((s8v*)d)[i] = ov;
  }
}

// ---------------- QKV GEMM: C = (A[M,K] * B[N,K]^T + bias) * sc ----------------
// 128x64 tile, BK=64 (16 K-steps), 4 waves 2x2 (each 64x32). Grid (32,16,3) = 6 blk/CU.
// G21 swizzled LDS: rows of 128B, chunk g XOR'd with row&7 (involution, bits 4-6).
__global__ __launch_bounds__(256) void gemm_qkv(
    const u16* __restrict__ A,
    const u16* __restrict__ B0, const u16* __restrict__ B1, const u16* __restrict__ B2,
    const float* __restrict__ bias0, const float* __restrict__ bias1, const float* __restrict__ bias2,
    const float sc0, const float sc1, const float sc2,
    void* C0, void* C1, void* C2,
    const int Ksz)
{
  const int bm = blockIdx.x;
  const int bn = blockIdx.y;
  const int z  = blockIdx.z;

  const u16* Bp; const float* bias; void* Cp; float sc;
  if (z == 0)      { Bp = B0; bias = bias0; Cp = C0; sc = sc0; }
  else if (z == 1) { Bp = B1; bias = bias1; Cp = C1; sc = sc1; }
  else             { Bp = B2; bias = bias2; Cp = C2; sc = sc2; }

  __shared__ __align__(16) u16 As[128 * 64];   // 16 KB, swizzled
  __shared__ __align__(16) u16 Bs[64 * 64];    //  8 KB, swizzled

  const int t  = threadIdx.x;
  const int w  = t >> 6;
  const int l  = t & 63;
  const int lr = l & 15;
  const int lg = l >> 4;
  const int wr = w >> 1;
  const int wc = w & 1;

  const int trow = t >> 3;                       // 0..31
  const int gsc  = ((t & 7) ^ (trow & 7)) * 8;   // u16 offset in row

  const u16* gA = A  + (size_t)(bm * 128 + trow) * Ksz + gsc;
  const u16* gB = Bp + (size_t)(bn * 64  + trow) * Ksz + gsc;
  const size_t rk32 = (size_t)32 * Ksz;

  const f4v fzero = {0.f, 0.f, 0.f, 0.f};
  f4v acc[4][2];
#pragma unroll
  for (int m = 0; m < 4; ++m)
#pragma unroll
    for (int n = 0; n < 2; ++n) acc[m][n] = fzero;

  const int nk = Ksz >> 6;   // BK=64
  for (int kt = 0; kt < nk; ++kt) {
    if (kt) __syncthreads();
    gload_lds16(gA,            &As[t * 8]);
    gload_lds16(gA + rk32,     &As[2048 + t * 8]);
    gload_lds16(gA + 2 * rk32, &As[4096 + t * 8]);
    gload_lds16(gA + 3 * rk32, &As[6144 + t * 8]);
    gload_lds16(gB,            &Bs[t * 8]);
    gload_lds16(gB + rk32,     &Bs[2048 + t * 8]);
    gA += 64; gB += 64;
    __syncthreads();

#pragma unroll
    for (int kk = 0; kk < 2; ++kk) {
      s8v af[4], bfr[2];
#pragma unroll
      for (int m = 0; m < 4; ++m) {
        const int R = wr * 64 + m * 16 + lr;
        const int g = (kk * 4 + lg) ^ (lr & 7);
        af[m] = *(const s8v*)&As[R * 64 + g * 8];
      }
#pragma unroll
      for (int n = 0; n < 2; ++n) {
        const int R = wc * 32 + n * 16 + lr;
        const int g = (kk * 4 + lg) ^ (lr & 7);
        bfr[n] = *(const s8v*)&Bs[R * 64 + g * 8];
      }
#pragma unroll
      for (int m = 0; m < 4; ++m)
#pragma unroll
        for (int n = 0; n < 2; ++n)
          acc[m][n] = mfma16(af[m], bfr[n], acc[m][n]);
    }
  }

  // epilogue: C/D layout col = lane&15, row = (lane>>4)*4 + reg  (r11-verified)
  if (z == 1) {
#pragma unroll
    for (int n = 0; n < 2; ++n) {
      const int col = bn * 64 + wc * 32 + n * 16 + lr;
      const float bv = bias[col];
      const int h  = col >> 6;
      const int d6 = col & 63;
      const int j  = d6 >> 4;
      const int hic = (d6 >> 3) & 1;
      const int e  = d6 & 7;
#pragma unroll
      for (int m = 0; m < 4; ++m) {
#pragma unroll
        for (int r = 0; r < 4; ++r) {
          const int row = bm * 128 + wr * 64 + m * 16 + lg * 4 + r;
          const int bb = row >> 11;
          const int s  = row & (SEQ - 1);
          const int tile = s >> 5;
          const int l31r = s & 31;
          const size_t idx = ((((size_t)(bb * NH + h) * 64 + tile) * 4 + j) * 512)
                           + (size_t)hic * 256 + (size_t)l31r * 8 + e;
          ((u16*)Cp)[idx] = f2b((acc[m][n][r] + bv) * sc);
        }
      }
    }
  } else if (z == 2) {
#pragma unroll
    for (int n = 0; n < 2; ++n) {
      const int col = bn * 64 + wc * 32 + n * 16 + lr;
      const float bv = bias[col];
      const int h    = col >> 6;
      const int dt   = (col >> 5) & 1;
      const int l31c = col & 31;
#pragma unroll
      for (int m = 0; m < 4; ++m) {
        const int row0 = bm * 128 + wr * 64 + m * 16 + lg * 4;
        const int bb = row0 >> 11;
        const int s0 = row0 & (SEQ - 1);
        const int tile = s0 >> 5;
        const int u    = (s0 >> 4) & 1;
        const int hiw  = (s0 >> 3) & 1;
        const int e0   = s0 & 7;
        const size_t idx = ((((size_t)(bb * NH + h) * 64 + tile) * 2 + u) * 2 + dt) * 512
                         + (size_t)hiw * 256 + (size_t)l31c * 8 + e0;
        ushort4 pk;
        pk.x = f2b((acc[m][n][0] + bv) * sc);
        pk.y = f2b((acc[m][n][1] + bv) * sc);
        pk.z = f2b((acc[m][n][2] + bv) * sc);
        pk.w = f2b((acc[m][n][3] + bv) * sc);
        *(ushort4*)((u16*)Cp + idx) = pk;
      }
    }
  } else {
#pragma unroll
    for (int n = 0; n < 2; ++n) {
      const int col = bn * 64 + wc * 32 + n * 16 + lr;
      const float bv = bias[col];
#pragma unroll
      for (int m = 0; m < 4; ++m) {
#pragma unroll
        for (int r = 0; r < 4; ++r) {
          const int row = bm * 128 + wr * 64 + m * 16 + lg * 4 + r;
          ((u16*)Cp)[(size_t)row * HID + col] = f2b((acc[m][n][r] + bv) * sc);
        }
      }
    }
  }
}

// ---------------- output projection: C[M,N] f32 = A[M,K] * B[N,K]^T + bias ----------------
// 64x64 tile, BK=128 (8 K-steps, 16 MFMA/wave per drain), 4 waves 2x2 (each 32x32).
// G21 swizzled LDS: rows of 256B = 16 chunks; store global chunk c^(row&15) at chunk c.
__global__ __launch_bounds__(256) void gemm_out(
    const u16* __restrict__ A, const u16* __restrict__ B,
    const float* __restrict__ bias, float* __restrict__ C, const int Ksz, const int Nsz)
{
  const int bm = blockIdx.x;
  const int bn = blockIdx.y;

  __shared__ __align__(16) u16 As[64 * 128];   // 16 KB
  __shared__ __align__(16) u16 Bs[64 * 128];   // 16 KB

  const int t  = threadIdx.x;
  const int w  = t >> 6;
  const int l  = t & 63;
  const int lr = l & 15;
  const int lg = l >> 4;
  const int wr = w >> 1;
  const int wc = w & 1;

  const int trow = t >> 4;                        // 0..15
  const int gsc  = ((t & 15) ^ trow) * 8;         // u16 offset in row (chunk swizzle)

  const u16* gA = A + (size_t)(bm * 64 + trow) * Ksz + gsc;
  const u16* gB = B + (size_t)(bn * 64 + trow) * Ksz + gsc;
  const size_t rk16 = (size_t)16 * Ksz;

  const f4v fzero = {0.f, 0.f, 0.f, 0.f};
  f4v acc[2][2];
#pragma unroll
  for (int m = 0; m < 2; ++m)
#pragma unroll
    for (int n = 0; n < 2; ++n) acc[m][n] = fzero;

  const int nk = Ksz >> 7;   // BK=128
  for (int kt = 0; kt < nk; ++kt) {
    if (kt) __syncthreads();
    gload_lds16(gA,            &As[t * 8]);           // rows  0..15
    gload_lds16(gA + rk16,     &As[2048 + t * 8]);    // rows 16..31
    gload_lds16(gA + 2 * rk16, &As[4096 + t * 8]);    // rows 32..47
    gload_lds16(gA + 3 * rk16, &As[6144 + t * 8]);    // rows 48..63
    gload_lds16(gB,            &Bs[t * 8]);
    gload_lds16(gB + rk16,     &Bs[2048 + t * 8]);
    gload_lds16(gB + 2 * rk16, &Bs[4096 + t * 8]);
    gload_lds16(gB + 3 * rk16, &Bs[6144 + t * 8]);
    gA += 128; gB += 128;
    __syncthreads();

#pragma unroll
    for (int kk = 0; kk < 4; ++kk) {
      s8v af[2], bfr[2];
#pragma unroll
      for (int m = 0; m < 2; ++m) {
        const int R = wr * 32 + m * 16 + lr;
        const int g = (kk * 4 + lg) ^ lr;
        af[m] = *(const s8v*)&As[R * 128 + g * 8];
      }
#pragma unroll
      for (int n = 0; n < 2; ++n) {
        const int R = wc * 32 + n * 16 + lr;
        const int g = (kk * 4 + lg) ^ lr;
        bfr[n] = *(const s8v*)&Bs[R * 128 + g * 8];
      }
#pragma unroll
      for (int m = 0; m < 2; ++m)
#pragma unroll
        for (int n = 0; n < 2; ++n)
          acc[m][n] = mfma16(af[m], bfr[n], acc[m][n]);
    }
  }

#pragma unroll
  for (int n = 0; n < 2; ++n) {
    const int col = bn * 64 + wc * 32 + n * 16 + lr;
    const float bv = bias[col];
#pragma unroll
    for (int m = 0; m < 2; ++m) {
#pragma unroll
      for (int r = 0; r < 4; ++r) {
        const int row = bm * 64 + wr * 32 + m * 16 + lg * 4 + r;
        C[(size_t)row * Nsz + col] = acc[m][n][r] + bv;
      }
    }
  }
}

// ---------------- fused causal attention (swapped QK^T, 32x32 MFMA) ----------------
// grid (16, 2, 64), 256 threads = 4 waves: block = (head, batch, one qt = 63-z, LPT).
// 2048 blocks = 8 blocks/CU = 32 waves/CU; LPT order backfills the triangular tail.
// K/V from fragment-paged K'/V' (lane-contiguous 1KB loads). 4 waves split KV tiles
// by kt % 4; lane-local softmax; 4-way flash merge (bf16 Oacc).
// S^T = mfma(A=K, B=Q): lane l holds S[q = l&31, kv = (r&3)+8*(r>>2)+4*(l>>5)].
// O regs: o[r] = O[q = (r&3)+8*(r>>2)+4*hi, d = l&31 (+32 for o1)]  (C/D layout).
__global__ __launch_bounds__(256, 4) void attn_fused(
    const u16* __restrict__ Qm, const u16* __restrict__ Kp,
    const u16* __restrict__ Vp, u16* __restrict__ Om)
{
  __shared__ __align__(16) u16 Oaccb[4 * 32 * 66];   // bf16 partials (18 KB total LDS)
  __shared__ float Msh[4][32];
  __shared__ float Lsh[4][32];
  __shared__ float Rsh[4][32];

  const int h  = blockIdx.x;
  const int b  = blockIdx.y;
  const int qt = 63 - blockIdx.z;   // longest-first dispatch (LPT)
  const int t  = threadIdx.x;
  const int w  = t >> 6;        // 0..3
  const int l  = t & 63;
  const int l31 = l & 31;
  const int hi  = l >> 5;
  const int hi8 = hi * 8;
  const int hi4 = hi * 4;

  const u16* Qb = Qm + (size_t)(b * SEQ) * HID + h * DH;
  const u16* Kpb = Kp + (size_t)(b * NH + h) * 64 * 2048 + (size_t)l * 8;
  const u16* Vpb = Vp + (size_t)(b * NH + h) * 64 * 2048 + (size_t)l * 8;

  const f16v z16 = {0.f,0.f,0.f,0.f,0.f,0.f,0.f,0.f,0.f,0.f,0.f,0.f,0.f,0.f,0.f,0.f};

  const int qr0 = qt * 32;

  // Q fragments (B-operand): lane -> col q = l31, k = d
  const u16* qrow = Qb + (size_t)(qr0 + l31) * HID + hi8;
  const s8v q0 = *(const s8v*)(qrow);
  const s8v q1 = *(const s8v*)(qrow + 16);
  const s8v q2 = *(const s8v*)(qrow + 32);
  const s8v q3 = *(const s8v*)(qrow + 48);

  f16v o0 = z16, o1 = z16;
  float mrow = -1e30f, lrow = 0.f;

  for (int kt = w; kt <= qt; kt += 4) {
    // K fragments: lane-contiguous pages (j = 0..3)
    const u16* ktb = Kpb + (size_t)kt * 2048;
    const s8v ak0 = *(const s8v*)(ktb);
    const s8v ak1 = *(const s8v*)(ktb + 512);
    const s8v ak2 = *(const s8v*)(ktb + 1024);
    const s8v ak3 = *(const s8v*)(ktb + 1536);
    // V^T fragments: lane-contiguous pages (u, dt)
    const u16* vtb = Vpb + (size_t)kt * 2048;
    const s8v bv00 = *(const s8v*)(vtb);          // u=0 dt=0
    const s8v bv01 = *(const s8v*)(vtb + 512);    // u=0 dt=1
    const s8v bv10 = *(const s8v*)(vtb + 1024);   // u=1 dt=0
    const s8v bv11 = *(const s8v*)(vtb + 1536);   // u=1 dt=1

    // S^T tile
    f16v st = z16;
    __builtin_amdgcn_s_setprio(1);
    st = mfma32(ak0, q0, st);
    st = mfma32(ak1, q1, st);
    st = mfma32(ak2, q2, st);
    st = mfma32(ak3, q3, st);
    __builtin_amdgcn_s_setprio(0);

    if (kt == qt) {   // causal mask, diagonal tile only (kv0 == qr0)
#pragma unroll
      for (int r = 0; r < 16; ++r)
        if (((r & 3) + 8 * (r >> 2) + hi4) > l31) st[r] = -1e30f;
    }

    // row max: in-register tree + cross-half swap
    float a0 = fmaxf(st[0], st[8]),  a1 = fmaxf(st[1], st[9]);
    float a2 = fmaxf(st[2], st[10]), a3 = fmaxf(st[3], st[11]);
    float a4 = fmaxf(st[4], st[12]), a5 = fmaxf(st[5], st[13]);
    float a6 = fmaxf(st[6], st[14]), a7 = fmaxf(st[7], st[15]);
    float b0 = fmaxf(a0, a4), b1 = fmaxf(a1, a5), b2 = fmaxf(a2, a6), b3 = fmaxf(a3, a7);
    float tm = fmaxf(fmaxf(b0, b1), fmaxf(b2, b3));
    tm = fmaxf(tm, __shfl_xor(tm, 32, 64));

    // defer-max: rescale only when some row's max grew past THR2
    if (!__all((tm - mrow <= THR2) ? 1 : 0)) {
      const float mn = fmaxf(mrow, tm);
      const float rs = fexp2(mrow - mn);
      mrow = mn;
      lrow *= rs;
      if (l < 32) Rsh[w][l31] = rs;
#pragma unroll
      for (int r = 0; r < 16; ++r) {
        const float f = Rsh[w][(r & 3) + 8 * (r >> 2) + hi4];
        o0[r] *= f; o1[r] *= f;
      }
    }

    // P = 2^(s - m), lane-local
    float p[16];
#pragma unroll
    for (int r = 0; r < 16; ++r) p[r] = fexp2(st[r] - mrow);

    // row sum: tree + cross-half swap
    float u0 = p[0]+p[8],  u1 = p[1]+p[9],  u2 = p[2]+p[10], u3 = p[3]+p[11];
    float u4 = p[4]+p[12], u5 = p[5]+p[13], u6 = p[6]+p[14], u7 = p[7]+p[15];
    float v0 = u0+u4, v1 = u1+u5, v2 = u2+u6, v3 = u3+u7;
    float ts = (v0+v1) + (v2+v3);
    ts += __shfl_xor(ts, 32, 64);
    lrow += ts;

    // P -> bf16 A-fragments via cvt_pk + permlane32_swap (m214 recipe).
    // pswap(X, Y): X <- {X.lo31, Y.lo31} (= word j), Y <- {X.hi31, Y.hi31} (= word j+2)
    uint32_t A0 = pkbf16(p[0], p[1]),  A1 = pkbf16(p[2], p[3]);
    uint32_t B0 = pkbf16(p[4], p[5]),  B1 = pkbf16(p[6], p[7]);
    pswap(A0, B0); pswap(A1, B1);
    uint32_t C0 = pkbf16(p[8], p[9]),  C1 = pkbf16(p[10], p[11]);
    uint32_t D0 = pkbf16(p[12], p[13]), D1 = pkbf16(p[14], p[15]);
    pswap(C0, D0); pswap(C1, D1);
    union { uint32_t wd[4]; s8v v; } f0, f1;
    f0.wd[0] = A0; f0.wd[1] = A1; f0.wd[2] = B0; f0.wd[3] = B1;   // kv 0..15
    f1.wd[0] = C0; f1.wd[1] = C1; f1.wd[2] = D0; f1.wd[3] = D1;   // kv 16..31

    // O += P V
    __builtin_amdgcn_s_setprio(1);
    o0 = mfma32(f0.v, bv00, o0);
    o0 = mfma32(f1.v, bv10, o0);
    o1 = mfma32(f0.v, bv01, o1);
    o1 = mfma32(f1.v, bv11, o1);
    __builtin_amdgcn_s_setprio(0);
  }

  // ---- flash merge of the 4 waves' partials (bf16 Oacc) ----
  if (l < 32) { Msh[w][l31] = mrow; Lsh[w][l31] = lrow; }
  __syncthreads();

  float fr[16];
#pragma unroll
  for (int r = 0; r < 16; ++r) {
    const int q = (r & 3) + 8 * (r >> 2) + hi4;
    float M = fmaxf(fmaxf(Msh[0][q], Msh[1][q]), fmaxf(Msh[2][q], Msh[3][q]));
    // own-wave max for row q from Msh (register mrow is row l31's max)
    fr[r] = fexp2(Msh[w][q] - M);
  }
#pragma unroll
  for (int r = 0; r < 16; ++r) {
    const int q = (r & 3) + 8 * (r >> 2) + hi4;
    Oaccb[(w * 32 + q) * 66 + l31]      = f2b(o0[r] * fr[r]);
    Oaccb[(w * 32 + q) * 66 + 33 + l31] = f2b(o1[r] * fr[r]);
  }
  __syncthreads();

  // sum phase: wave w -> rows w*8..w*8+7, lane l -> column d
#pragma unroll
  for (int j = 0; j < 8; ++j) {
    const int row = w * 8 + j;
    float M = fmaxf(fmaxf(Msh[0][row], Msh[1][row]), fmaxf(Msh[2][row], Msh[3][row]));
    float lt = 0.f;
#pragma unroll
    for (int wp = 0; wp < 4; ++wp) lt += fexp2(Msh[wp][row] - M) * Lsh[wp][row];
    const int cof = (l >= 32) ? (33 + l31) : l31;
    float v = 0.f;
#pragma unroll
    for (int wp = 0; wp < 4; ++wp) v += b2f(Oaccb[(wp * 32 + row) * 66 + cof]);
    Om[(size_t)(b * SEQ + qr0 + row) * HID + h * DH + l] = f2b(v / lt);
  }
}

// ---------------- launch ----------------
extern "C" void kernel_launch(void* const* d_in, const int* in_sizes, int n_in,
                              void* d_out, int out_size, void* d_ws, size_t ws_size,
                              hipStream_t stream) {
  const float* x  = (const float*)d_in[0];
  const float* Wq = (const float*)d_in[1];
  const float* bq = (const float*)d_in[2];
  const float* Wk = (const float*)d_in[3];
  const float* bk = (const float*)d_in[4];
  const float* Wv = (const float*)d_in[5];
  const float* bv = (const float*)d_in[6];
  const float* Wm = (const float*)d_in[7];
  const float* bm = (const float*)d_in[8];
  float* out = (float*)d_out;

  u16* xb  = (u16*)d_ws;
  u16* Wqb = xb  + (size_t)MROWS * HID;
  u16* Wkb = Wqb + (size_t)HID * HID;
  u16* Wvb = Wkb + (size_t)HID * HID;
  u16* Wmb = Wvb + (size_t)HID * HID;
  u16* Qm  = Wmb + (size_t)HID * HID;
  u16* Kp  = Qm  + (size_t)MROWS * HID;   // K fragment-paged
  u16* Vp  = Kp  + (size_t)MROWS * HID;   // V fragment-paged
  u16* att = Vp  + (size_t)MROWS * HID;

  cvt5<<<dim3(512, 5, 1), 256, 0, stream>>>(x, Wq, Wk, Wv, Wm, xb, Wqb, Wkb, Wvb, Wmb);
  gemm_qkv<<<dim3(32, 16, 3), 256, 0, stream>>>(
      xb, Wqb, Wkb, Wvb, bq, bk, bv, CLOG, 1.f, 1.f, Qm, Kp, Vp, HID);
  attn_fused<<<dim3(16, 2, 64), 256, 0, stream>>>(Qm, Kp, Vp, att);
  gemm_out<<<dim3(64, 16), 256, 0, stream>>>(att, Wmb, bm, out, HID, HID);
}

// Round 24
// 94.109 us; speedup vs baseline: 1.0633x; 1.0049x over previous
//
#include <hip/hip_runtime.h>
#include <hip/hip_bf16.h>
#include <cstdint>
#include <cstddef>

typedef unsigned short u16;
typedef short s8v __attribute__((ext_vector_type(8)));
typedef float f4v __attribute__((ext_vector_type(4)));
typedef float f16v __attribute__((ext_vector_type(16)));

#define SEQ   2048
#define BSZ   2
#define HID   1024
#define NH    16
#define DH    64
#define MROWS (BSZ*SEQ)
#define CLOG  0.18033688011112042f   // log2(e)/sqrt(64), folded into Q
#define THR2  6.0f                   // defer-max threshold (log2 units): P <= 64

// f32 -> bf16 round-to-nearest-even
__device__ __forceinline__ u16 f2b(float x) {
  union { float f; uint32_t u; } c; c.f = x;
  uint32_t r = (c.u + 0x7fffu + ((c.u >> 16) & 1u)) >> 16;
  return (u16)r;
}
__device__ __forceinline__ float b2f(u16 v) {
  union { uint32_t u; float f; } c; c.u = (uint32_t)v << 16;
  return c.f;
}

__device__ __forceinline__ f4v mfma16(s8v a, s8v b, f4v c) {
  return __builtin_amdgcn_mfma_f32_16x16x32_bf16(a, b, c, 0, 0, 0);
}
__device__ __forceinline__ f16v mfma32(s8v a, s8v b, f16v c) {
  return __builtin_amdgcn_mfma_f32_32x32x16_bf16(a, b, c, 0, 0, 0);
}

__device__ __forceinline__ float fexp2(float x) {
#if __has_builtin(__builtin_amdgcn_exp2f)
  return __builtin_amdgcn_exp2f(x);
#else
  return exp2f(x);
#endif
}

// pack 2 f32 -> bf16x2 (lo = a, hi = b)
__device__ __forceinline__ uint32_t pkbf16(float a, float b) {
  uint32_t d;
  asm("v_cvt_pk_bf16_f32 %0, %1, %2" : "=v"(d) : "v"(a), "v"(b));
  return d;
}
// v_permlane32_swap_b32 dst,src: new dst = {dst.lo31, src.lo31},
//                                new src = {dst.hi31, src.hi31}
// NOTE: only safe when the two operands hold DISTINCT values (else the
// allocator may coalesce them into one register -> self-swap garbage; r23).
__device__ __forceinline__ void pswap(uint32_t& x, uint32_t& y) {
  asm("v_permlane32_swap_b32 %0, %1" : "+v"(x), "+v"(y));
}

typedef __attribute__((address_space(1))) const void gas_void;
typedef __attribute__((address_space(3))) void las_void;
__device__ __forceinline__ void gload_lds16(const void* g, void* l) {
  __builtin_amdgcn_global_load_lds((gas_void*)g, (las_void*)l, 16, 0, 0);
}

// ---------------- f32 -> bf16 conversion (5 arrays fused) ----------------
__global__ __launch_bounds__(256) void cvt5(
    const float* __restrict__ s0, const float* __restrict__ s1,
    const float* __restrict__ s2, const float* __restrict__ s3,
    const float* __restrict__ s4,
    u16* __restrict__ d0, u16* __restrict__ d1, u16* __restrict__ d2,
    u16* __restrict__ d3, u16* __restrict__ d4)
{
  const float* s; u16* d; int n;
  switch (blockIdx.y) {
    case 0:  s = s0; d = d0; n = MROWS*HID; break;
    case 1:  s = s1; d = d1; n = HID*HID;   break;
    case 2:  s = s2; d = d2; n = HID*HID;   break;
    case 3:  s = s3; d = d3; n = HID*HID;   break;
    default: s = s4; d = d4; n = HID*HID;   break;
  }
  const int n8 = n >> 3;
  const int stride = gridDim.x * blockDim.x;
  for (int i = blockIdx.x * blockDim.x + threadIdx.x; i < n8; i += stride) {
    const float4* p = (const float4*)s + (size_t)i * 2;
    float4 a = p[0], b = p[1];
    s8v ov;
    ov[0] = (short)f2b(a.x); ov[1] = (short)f2b(a.y);
    ov[2] = (short)f2b(a.z); ov[3] = (short)f2b(a.w);
    ov[4] = (short)f2b(b.x); ov[5] = (short)f2b(b.y);
    ov[6] = (short)f2b(b.z); ov[7] = (short)f2b(b.w);
    ((s8v*)d)[i] = ov;
  }
}

// ---------------- QKV GEMM: C = (A[M,K] * B[N,K]^T + bias) * sc ----------------
// 128x64 tile, BK=64 (16 K-steps), 4 waves 2x2 (each 64x32). Grid (32,16,3) = 6 blk/CU.
// G21 swizzled LDS: rows of 128B, chunk g XOR'd with row&7 (involution, bits 4-6).
__global__ __launch_bounds__(256) void gemm_qkv(
    const u16* __restrict__ A,
    const u16* __restrict__ B0, const u16* __restrict__ B1, const u16* __restrict__ B2,
    const float* __restrict__ bias0, const float* __restrict__ bias1, const float* __restrict__ bias2,
    const float sc0, const float sc1, const float sc2,
    void* C0, void* C1, void* C2,
    const int Ksz)
{
  const int bm = blockIdx.x;
  const int bn = blockIdx.y;
  const int z  = blockIdx.z;

  const u16* Bp; const float* bias; void* Cp; float sc;
  if (z == 0)      { Bp = B0; bias = bias0; Cp = C0; sc = sc0; }
  else if (z == 1) { Bp = B1; bias = bias1; Cp = C1; sc = sc1; }
  else             { Bp = B2; bias = bias2; Cp = C2; sc = sc2; }

  __shared__ __align__(16) u16 As[128 * 64];   // 16 KB, swizzled
  __shared__ __align__(16) u16 Bs[64 * 64];    //  8 KB, swizzled

  const int t  = threadIdx.x;
  const int w  = t >> 6;
  const int l  = t & 63;
  const int lr = l & 15;
  const int lg = l >> 4;
  const int wr = w >> 1;
  const int wc = w & 1;

  const int trow = t >> 3;                       // 0..31
  const int gsc  = ((t & 7) ^ (trow & 7)) * 8;   // u16 offset in row

  const u16* gA = A  + (size_t)(bm * 128 + trow) * Ksz + gsc;
  const u16* gB = Bp + (size_t)(bn * 64  + trow) * Ksz + gsc;
  const size_t rk32 = (size_t)32 * Ksz;

  const f4v fzero = {0.f, 0.f, 0.f, 0.f};
  f4v acc[4][2];
#pragma unroll
  for (int m = 0; m < 4; ++m)
#pragma unroll
    for (int n = 0; n < 2; ++n) acc[m][n] = fzero;

  const int nk = Ksz >> 6;   // BK=64
  for (int kt = 0; kt < nk; ++kt) {
    if (kt) __syncthreads();
    gload_lds16(gA,            &As[t * 8]);
    gload_lds16(gA + rk32,     &As[2048 + t * 8]);
    gload_lds16(gA + 2 * rk32, &As[4096 + t * 8]);
    gload_lds16(gA + 3 * rk32, &As[6144 + t * 8]);
    gload_lds16(gB,            &Bs[t * 8]);
    gload_lds16(gB + rk32,     &Bs[2048 + t * 8]);
    gA += 64; gB += 64;
    __syncthreads();

#pragma unroll
    for (int kk = 0; kk < 2; ++kk) {
      s8v af[4], bfr[2];
#pragma unroll
      for (int m = 0; m < 4; ++m) {
        const int R = wr * 64 + m * 16 + lr;
        const int g = (kk * 4 + lg) ^ (lr & 7);
        af[m] = *(const s8v*)&As[R * 64 + g * 8];
      }
#pragma unroll
      for (int n = 0; n < 2; ++n) {
        const int R = wc * 32 + n * 16 + lr;
        const int g = (kk * 4 + lg) ^ (lr & 7);
        bfr[n] = *(const s8v*)&Bs[R * 64 + g * 8];
      }
#pragma unroll
      for (int m = 0; m < 4; ++m)
#pragma unroll
        for (int n = 0; n < 2; ++n)
          acc[m][n] = mfma16(af[m], bfr[n], acc[m][n]);
    }
  }

  // epilogue: C/D layout col = lane&15, row = (lane>>4)*4 + reg  (r11-verified)
  if (z == 1) {
#pragma unroll
    for (int n = 0; n < 2; ++n) {
      const int col = bn * 64 + wc * 32 + n * 16 + lr;
      const float bv = bias[col];
      const int h  = col >> 6;
      const int d6 = col & 63;
      const int j  = d6 >> 4;
      const int hic = (d6 >> 3) & 1;
      const int e  = d6 & 7;
#pragma unroll
      for (int m = 0; m < 4; ++m) {
#pragma unroll
        for (int r = 0; r < 4; ++r) {
          const int row = bm * 128 + wr * 64 + m * 16 + lg * 4 + r;
          const int bb = row >> 11;
          const int s  = row & (SEQ - 1);
          const int tile = s >> 5;
          const int l31r = s & 31;
          const size_t idx = ((((size_t)(bb * NH + h) * 64 + tile) * 4 + j) * 512)
                           + (size_t)hic * 256 + (size_t)l31r * 8 + e;
          ((u16*)Cp)[idx] = f2b((acc[m][n][r] + bv) * sc);
        }
      }
    }
  } else if (z == 2) {
#pragma unroll
    for (int n = 0; n < 2; ++n) {
      const int col = bn * 64 + wc * 32 + n * 16 + lr;
      const float bv = bias[col];
      const int h    = col >> 6;
      const int dt   = (col >> 5) & 1;
      const int l31c = col & 31;
#pragma unroll
      for (int m = 0; m < 4; ++m) {
        const int row0 = bm * 128 + wr * 64 + m * 16 + lg * 4;
        const int bb = row0 >> 11;
        const int s0 = row0 & (SEQ - 1);
        const int tile = s0 >> 5;
        const int u    = (s0 >> 4) & 1;
        const int hiw  = (s0 >> 3) & 1;
        const int e0   = s0 & 7;
        const size_t idx = ((((size_t)(bb * NH + h) * 64 + tile) * 2 + u) * 2 + dt) * 512
                         + (size_t)hiw * 256 + (size_t)l31c * 8 + e0;
        ushort4 pk;
        pk.x = f2b((acc[m][n][0] + bv) * sc);
        pk.y = f2b((acc[m][n][1] + bv) * sc);
        pk.z = f2b((acc[m][n][2] + bv) * sc);
        pk.w = f2b((acc[m][n][3] + bv) * sc);
        *(ushort4*)((u16*)Cp + idx) = pk;
      }
    }
  } else {
#pragma unroll
    for (int n = 0; n < 2; ++n) {
      const int col = bn * 64 + wc * 32 + n * 16 + lr;
      const float bv = bias[col];
#pragma unroll
      for (int m = 0; m < 4; ++m) {
#pragma unroll
        for (int r = 0; r < 4; ++r) {
          const int row = bm * 128 + wr * 64 + m * 16 + lg * 4 + r;
          ((u16*)Cp)[(size_t)row * HID + col] = f2b((acc[m][n][r] + bv) * sc);
        }
      }
    }
  }
}

// ---------------- output projection: C[M,N] f32 = A[M,K] * B[N,K]^T + bias ----------------
// 64x64 tile, BK=128 (8 K-steps, 16 MFMA/wave per drain), 4 waves 2x2 (each 32x32).
// G21 swizzled LDS: rows of 256B = 16 chunks; store global chunk c^(row&15) at chunk c.
__global__ __launch_bounds__(256) void gemm_out(
    const u16* __restrict__ A, const u16* __restrict__ B,
    const float* __restrict__ bias, float* __restrict__ C, const int Ksz, const int Nsz)
{
  const int bm = blockIdx.x;
  const int bn = blockIdx.y;

  __shared__ __align__(16) u16 As[64 * 128];   // 16 KB
  __shared__ __align__(16) u16 Bs[64 * 128];   // 16 KB

  const int t  = threadIdx.x;
  const int w  = t >> 6;
  const int l  = t & 63;
  const int lr = l & 15;
  const int lg = l >> 4;
  const int wr = w >> 1;
  const int wc = w & 1;

  const int trow = t >> 4;                        // 0..15
  const int gsc  = ((t & 15) ^ trow) * 8;         // u16 offset in row (chunk swizzle)

  const u16* gA = A + (size_t)(bm * 64 + trow) * Ksz + gsc;
  const u16* gB = B + (size_t)(bn * 64 + trow) * Ksz + gsc;
  const size_t rk16 = (size_t)16 * Ksz;

  const f4v fzero = {0.f, 0.f, 0.f, 0.f};
  f4v acc[2][2];
#pragma unroll
  for (int m = 0; m < 2; ++m)
#pragma unroll
    for (int n = 0; n < 2; ++n) acc[m][n] = fzero;

  const int nk = Ksz >> 7;   // BK=128
  for (int kt = 0; kt < nk; ++kt) {
    if (kt) __syncthreads();
    gload_lds16(gA,            &As[t * 8]);           // rows  0..15
    gload_lds16(gA + rk16,     &As[2048 + t * 8]);    // rows 16..31
    gload_lds16(gA + 2 * rk16, &As[4096 + t * 8]);    // rows 32..47
    gload_lds16(gA + 3 * rk16, &As[6144 + t * 8]);    // rows 48..63
    gload_lds16(gB,            &Bs[t * 8]);
    gload_lds16(gB + rk16,     &Bs[2048 + t * 8]);
    gload_lds16(gB + 2 * rk16, &Bs[4096 + t * 8]);
    gload_lds16(gB + 3 * rk16, &Bs[6144 + t * 8]);
    gA += 128; gB += 128;
    __syncthreads();

#pragma unroll
    for (int kk = 0; kk < 4; ++kk) {
      s8v af[2], bfr[2];
#pragma unroll
      for (int m = 0; m < 2; ++m) {
        const int R = wr * 32 + m * 16 + lr;
        const int g = (kk * 4 + lg) ^ lr;
        af[m] = *(const s8v*)&As[R * 128 + g * 8];
      }
#pragma unroll
      for (int n = 0; n < 2; ++n) {
        const int R = wc * 32 + n * 16 + lr;
        const int g = (kk * 4 + lg) ^ lr;
        bfr[n] = *(const s8v*)&Bs[R * 128 + g * 8];
      }
#pragma unroll
      for (int m = 0; m < 2; ++m)
#pragma unroll
        for (int n = 0; n < 2; ++n)
          acc[m][n] = mfma16(af[m], bfr[n], acc[m][n]);
    }
  }

#pragma unroll
  for (int n = 0; n < 2; ++n) {
    const int col = bn * 64 + wc * 32 + n * 16 + lr;
    const float bv = bias[col];
#pragma unroll
    for (int m = 0; m < 2; ++m) {
#pragma unroll
      for (int r = 0; r < 4; ++r) {
        const int row = bm * 64 + wr * 32 + m * 16 + lg * 4 + r;
        C[(size_t)row * Nsz + col] = acc[m][n][r] + bv;
      }
    }
  }
}

// ---------------- fused causal attention (swapped QK^T, 32x32 MFMA) ----------------
// grid (16, 2, 64), 256 threads = 4 waves: block = (head, batch, one qt = 63-z, LPT).
// 2048 blocks = 8 blocks/CU = 32 waves/CU; LPT order backfills the triangular tail.
// Cross-half reduction via __shfl_xor (r22-verified); max tree in v_max3 triples.
// S^T = mfma(A=K, B=Q): lane l holds S[q = l&31, kv = (r&3)+8*(r>>2)+4*(l>>5)].
// O regs: o[r] = O[q = (r&3)+8*(r>>2)+4*hi, d = l&31 (+32 for o1)]  (C/D layout).
__global__ __launch_bounds__(256, 4) void attn_fused(
    const u16* __restrict__ Qm, const u16* __restrict__ Kp,
    const u16* __restrict__ Vp, u16* __restrict__ Om)
{
  __shared__ __align__(16) u16 Oaccb[4 * 32 * 66];   // bf16 partials (18 KB total LDS)
  __shared__ float Msh[4][32];
  __shared__ float Lsh[4][32];
  __shared__ float Rsh[4][32];

  const int h  = blockIdx.x;
  const int b  = blockIdx.y;
  const int qt = 63 - blockIdx.z;   // longest-first dispatch (LPT)
  const int t  = threadIdx.x;
  const int w  = t >> 6;        // 0..3
  const int l  = t & 63;
  const int l31 = l & 31;
  const int hi  = l >> 5;
  const int hi8 = hi * 8;
  const int hi4 = hi * 4;

  const u16* Qb = Qm + (size_t)(b * SEQ) * HID + h * DH;
  const u16* Kpb = Kp + (size_t)(b * NH + h) * 64 * 2048 + (size_t)l * 8;
  const u16* Vpb = Vp + (size_t)(b * NH + h) * 64 * 2048 + (size_t)l * 8;

  const f16v z16 = {0.f,0.f,0.f,0.f,0.f,0.f,0.f,0.f,0.f,0.f,0.f,0.f,0.f,0.f,0.f,0.f};

  const int qr0 = qt * 32;

  // Q fragments (B-operand): lane -> col q = l31, k = d
  const u16* qrow = Qb + (size_t)(qr0 + l31) * HID + hi8;
  const s8v q0 = *(const s8v*)(qrow);
  const s8v q1 = *(const s8v*)(qrow + 16);
  const s8v q2 = *(const s8v*)(qrow + 32);
  const s8v q3 = *(const s8v*)(qrow + 48);

  f16v o0 = z16, o1 = z16;
  float mrow = -1e30f, lrow = 0.f;

  for (int kt = w; kt <= qt; kt += 4) {
    // K fragments: lane-contiguous pages (j = 0..3)
    const u16* ktb = Kpb + (size_t)kt * 2048;
    const s8v ak0 = *(const s8v*)(ktb);
    const s8v ak1 = *(const s8v*)(ktb + 512);
    const s8v ak2 = *(const s8v*)(ktb + 1024);
    const s8v ak3 = *(const s8v*)(ktb + 1536);
    // V^T fragments: lane-contiguous pages (u, dt)
    const u16* vtb = Vpb + (size_t)kt * 2048;
    const s8v bv00 = *(const s8v*)(vtb);          // u=0 dt=0
    const s8v bv01 = *(const s8v*)(vtb + 512);    // u=0 dt=1
    const s8v bv10 = *(const s8v*)(vtb + 1024);   // u=1 dt=0
    const s8v bv11 = *(const s8v*)(vtb + 1536);   // u=1 dt=1

    // S^T tile
    f16v st = z16;
    __builtin_amdgcn_s_setprio(1);
    st = mfma32(ak0, q0, st);
    st = mfma32(ak1, q1, st);
    st = mfma32(ak2, q2, st);
    st = mfma32(ak3, q3, st);
    __builtin_amdgcn_s_setprio(0);

    if (kt == qt) {   // causal mask, diagonal tile only (kv0 == qr0)
#pragma unroll
      for (int r = 0; r < 16; ++r)
        if (((r & 3) + 8 * (r >> 2) + hi4) > l31) st[r] = -1e30f;
    }

    // row max: v_max3-friendly triples (exact reassociation) + cross-half shfl
    const float g0 = fmaxf(fmaxf(st[0],  st[1]),  st[2]);
    const float g1 = fmaxf(fmaxf(st[3],  st[4]),  st[5]);
    const float g2 = fmaxf(fmaxf(st[6],  st[7]),  st[8]);
    const float g3 = fmaxf(fmaxf(st[9],  st[10]), st[11]);
    const float g4 = fmaxf(fmaxf(st[12], st[13]), st[14]);
    const float h0 = fmaxf(fmaxf(g0, g1), st[15]);
    const float h1 = fmaxf(fmaxf(g2, g3), g4);
    float tm = fmaxf(h0, h1);
    tm = fmaxf(tm, __shfl_xor(tm, 32, 64));

    // defer-max: rescale only when some row's max grew past THR2
    if (!__all((tm - mrow <= THR2) ? 1 : 0)) {
      const float mn = fmaxf(mrow, tm);
      const float rs = fexp2(mrow - mn);
      mrow = mn;
      lrow *= rs;
      if (l < 32) Rsh[w][l31] = rs;
#pragma unroll
      for (int r = 0; r < 16; ++r) {
        const float f = Rsh[w][(r & 3) + 8 * (r >> 2) + hi4];
        o0[r] *= f; o1[r] *= f;
      }
    }

    // P = 2^(s - m), lane-local
    float p[16];
#pragma unroll
    for (int r = 0; r < 16; ++r) p[r] = fexp2(st[r] - mrow);

    // row sum: tree + cross-half shfl
    float u0 = p[0]+p[8],  u1 = p[1]+p[9],  u2 = p[2]+p[10], u3 = p[3]+p[11];
    float u4 = p[4]+p[12], u5 = p[5]+p[13], u6 = p[6]+p[14], u7 = p[7]+p[15];
    float v0 = u0+u4, v1 = u1+u5, v2 = u2+u6, v3 = u3+u7;
    float ts = (v0+v1) + (v2+v3);
    ts += __shfl_xor(ts, 32, 64);
    lrow += ts;

    // P -> bf16 A-fragments via cvt_pk + permlane32_swap (m214 recipe).
    // pswap(X, Y): X <- {X.lo31, Y.lo31} (= word j), Y <- {X.hi31, Y.hi31} (= word j+2)
    uint32_t A0 = pkbf16(p[0], p[1]),  A1 = pkbf16(p[2], p[3]);
    uint32_t B0 = pkbf16(p[4], p[5]),  B1 = pkbf16(p[6], p[7]);
    pswap(A0, B0); pswap(A1, B1);
    uint32_t C0 = pkbf16(p[8], p[9]),  C1 = pkbf16(p[10], p[11]);
    uint32_t D0 = pkbf16(p[12], p[13]), D1 = pkbf16(p[14], p[15]);
    pswap(C0, D0); pswap(C1, D1);
    union { uint32_t wd[4]; s8v v; } f0, f1;
    f0.wd[0] = A0; f0.wd[1] = A1; f0.wd[2] = B0; f0.wd[3] = B1;   // kv 0..15
    f1.wd[0] = C0; f1.wd[1] = C1; f1.wd[2] = D0; f1.wd[3] = D1;   // kv 16..31

    // O += P V
    __builtin_amdgcn_s_setprio(1);
    o0 = mfma32(f0.v, bv00, o0);
    o0 = mfma32(f1.v, bv10, o0);
    o1 = mfma32(f0.v, bv01, o1);
    o1 = mfma32(f1.v, bv11, o1);
    __builtin_amdgcn_s_setprio(0);
  }

  // ---- flash merge of the 4 waves' partials (bf16 Oacc) ----
  if (l < 32) { Msh[w][l31] = mrow; Lsh[w][l31] = lrow; }
  __syncthreads();

  float fr[16];
#pragma unroll
  for (int r = 0; r < 16; ++r) {
    const int q = (r & 3) + 8 * (r >> 2) + hi4;
    float M = fmaxf(fmaxf(Msh[0][q], Msh[1][q]), fmaxf(Msh[2][q], Msh[3][q]));
    // own-wave max for row q from Msh (register mrow is row l31's max)
    fr[r] = fexp2(Msh[w][q] - M);
  }
#pragma unroll
  for (int r = 0; r < 16; ++r) {
    const int q = (r & 3) + 8 * (r >> 2) + hi4;
    Oaccb[(w * 32 + q) * 66 + l31]      = f2b(o0[r] * fr[r]);
    Oaccb[(w * 32 + q) * 66 + 33 + l31] = f2b(o1[r] * fr[r]);
  }
  __syncthreads();

  // sum phase: wave w -> rows w*8..w*8+7, lane l -> column d
#pragma unroll
  for (int j = 0; j < 8; ++j) {
    const int row = w * 8 + j;
    float M = fmaxf(fmaxf(Msh[0][row], Msh[1][row]), fmaxf(Msh[2][row], Msh[3][row]));
    float lt = 0.f;
#pragma unroll
    for (int wp = 0; wp < 4; ++wp) lt += fexp2(Msh[wp][row] - M) * Lsh[wp][row];
    const int cof = (l >= 32) ? (33 + l31) : l31;
    float v = 0.f;
#pragma unroll
    for (int wp = 0; wp < 4; ++wp) v += b2f(Oaccb[(wp * 32 + row) * 66 + cof]);
    Om[(size_t)(b * SEQ + qr0 + row) * HID + h * DH + l] = f2b(v / lt);
  }
}

// ---------------- launch ----------------
extern "C" void kernel_launch(void* const* d_in, const int* in_sizes, int n_in,
                              void* d_out, int out_size, void* d_ws, size_t ws_size,
                              hipStream_t stream) {
  const float* x  = (const float*)d_in[0];
  const float* Wq = (const float*)d_in[1];
  const float* bq = (const float*)d_in[2];
  const float* Wk = (const float*)d_in[3];
  const float* bk = (const float*)d_in[4];
  const float* Wv = (const float*)d_in[5];
  const float* bv = (const float*)d_in[6];
  const float* Wm = (const float*)d_in[7];
  const float* bm = (const float*)d_in[8];
  float* out = (float*)d_out;

  u16* xb  = (u16*)d_ws;
  u16* Wqb = xb  + (size_t)MROWS * HID;
  u16* Wkb = Wqb + (size_t)HID * HID;
  u16* Wvb = Wkb + (size_t)HID * HID;
  u16* Wmb = Wvb + (size_t)HID * HID;
  u16* Qm  = Wmb + (size_t)HID * HID;
  u16* Kp  = Qm  + (size_t)MROWS * HID;   // K fragment-paged
  u16* Vp  = Kp  + (size_t)MROWS * HID;   // V fragment-paged
  u16* att = Vp  + (size_t)MROWS * HID;

  cvt5<<<dim3(512, 5, 1), 256, 0, stream>>>(x, Wq, Wk, Wv, Wm, xb, Wqb, Wkb, Wvb, Wmb);
  gemm_qkv<<<dim3(32, 16, 3), 256, 0, stream>>>(
      xb, Wqb, Wkb, Wvb, bq, bk, bv, CLOG, 1.f, 1.f, Qm, Kp, Vp, HID);
  attn_fused<<<dim3(16, 2, 64), 256, 0, stream>>>(Qm, Kp, Vp, att);
  gemm_out<<<dim3(64, 16), 256, 0, stream>>>(att, Wmb, bm, out, HID, HID);
}